// Round 1
// 602.713 us; speedup vs baseline: 1.0269x; 1.0269x over previous
//
#include <hip/hip_runtime.h>

using half_t = _Float16;
using half8  = __attribute__((ext_vector_type(8))) _Float16;
using half4  = __attribute__((ext_vector_type(4))) _Float16;
using half2v = __attribute__((ext_vector_type(2))) _Float16;
using f32x4  = __attribute__((ext_vector_type(4))) float;
using f32x16 = __attribute__((ext_vector_type(16))) float;

#define MFMA(a, b, c)   __builtin_amdgcn_mfma_f32_16x16x32_f16((a), (b), (c), 0, 0, 0)
#define MFMA32(a, b, c) __builtin_amdgcn_mfma_f32_32x32x16_f16((a), (b), (c), 0, 0, 0)

// async global->LDS, 16 B per lane. LDS dest = wave-uniform base + lane*16.
#define GLL16(g, l)                                                     \
  __builtin_amdgcn_global_load_lds(                                     \
      (__attribute__((address_space(1))) void*)(g),                     \
      (__attribute__((address_space(3))) void*)(l), 16, 0, 0)

__device__ __forceinline__ half8 ld8(const half_t* p) { return *(const half8*)p; }

// ---------------------------------------------------------------- convert
__global__ void cvt_f32_f16(const float* __restrict__ src, half_t* __restrict__ dst, int n4) {
  int i = blockIdx.x * blockDim.x + threadIdx.x;
  if (i < n4) {
    f32x4 v = ((const f32x4*)src)[i];
    half4 h;
    h[0] = (half_t)v[0]; h[1] = (half_t)v[1]; h[2] = (half_t)v[2]; h[3] = (half_t)v[3];
    ((half4*)dst)[i] = h;
  }
}

// ---------------------------------------------------------------- GEMM (C = A * Bt^T), m97 structure
template <int EPI>
__global__ __launch_bounds__(256) void gemm_kernel(
    const half_t* __restrict__ A, const half_t* __restrict__ Bt,
    int M, int N, int K,
    half_t* __restrict__ oh, half_t* __restrict__ ov,
    float* __restrict__ of, const float* __restrict__ bias) {
  __shared__ alignas(16) half_t sA[128 * 32];
  __shared__ alignas(16) half_t sB[128 * 32];
  const int tid  = threadIdx.x;
  const int lane = tid & 63;
  const int w    = tid >> 6;
  const int c    = lane & 15;
  const int quad = lane >> 4;
  const int m0 = blockIdx.y * 128;
  const int n0 = blockIdx.x * 128;
  const int wm = (w & 1) * 64;
  const int wn = (w >> 1) * 64;

  f32x4 acc[4][4] = {};

  const int srow = tid >> 2;
  const int scol = (tid & 3) * 8;
  const half_t* Ag = A + (size_t)(m0 + srow) * K + scol;
  const half_t* Bg = Bt + (size_t)(n0 + srow) * K + scol;

  for (int k0 = 0; k0 < K; k0 += 32) {
    GLL16(Ag + k0,            sA + tid * 8);
    GLL16(Ag + k0 + 64 * K,   sA + tid * 8 + 2048);
    GLL16(Bg + k0,            sB + tid * 8);
    GLL16(Bg + k0 + 64 * K,   sB + tid * 8 + 2048);
    __syncthreads();
    half8 a[4], b[4];
#pragma unroll
    for (int i = 0; i < 4; ++i) a[i] = ld8(&sA[(wm + i * 16 + c) * 32 + quad * 8]);
#pragma unroll
    for (int j = 0; j < 4; ++j) b[j] = ld8(&sB[(wn + j * 16 + c) * 32 + quad * 8]);
#pragma unroll
    for (int i = 0; i < 4; ++i)
#pragma unroll
      for (int j = 0; j < 4; ++j) acc[i][j] = MFMA(a[i], b[j], acc[i][j]);
    __syncthreads();
  }

#pragma unroll
  for (int i = 0; i < 4; ++i) {
    const int mbase = m0 + wm + i * 16 + quad * 4;
#pragma unroll
    for (int j = 0; j < 4; ++j) {
      const int n = n0 + wn + j * 16 + c;
      if (EPI == 0) {
        const int bb = mbase >> 10, qi = mbase & 1023;
        const int hh = n >> 6, d = n & 63;
        half_t* p = oh + (((size_t)(bb * 16 + hh) * 1024 + qi) * 64 + d);
#pragma unroll
        for (int r = 0; r < 4; ++r) p[(size_t)r * 64] = (half_t)acc[i][j][r];
      } else if (EPI == 1) {
        const int bb = mbase >> 11, kvi = mbase & 2047;
        if (n < 1024) {
          const int hh = n >> 6, d = n & 63;
          half_t* p = oh + (((size_t)(bb * 16 + hh) * 2048 + kvi) * 64 + d);
#pragma unroll
          for (int r = 0; r < 4; ++r) p[(size_t)r * 64] = (half_t)acc[i][j][r];
        } else {
          const int nn = n - 1024;
          const int hh = nn >> 6, d = nn & 63;
          half4 hv;
#pragma unroll
          for (int r = 0; r < 4; ++r) hv[r] = (half_t)acc[i][j][r];
          *(half4*)&ov[((size_t)(bb * 16 + hh) * 64 + d) * 2048 + kvi] = hv;
        }
      } else {
        const float bv = bias[n];
#pragma unroll
        for (int r = 0; r < 4; ++r) of[(size_t)(mbase + r) * N + n] = acc[i][j][r] + bv;
      }
    }
  }
}

// ---------------------------------------------------------------- flash attention, swapped-QK 32x32 structure
// grid: bh*8 + qblk  (bh = b*16+h, qblk covers 128 q rows), 256 threads = 4 waves.
// Each wave owns a 32-q tile. Per 32-kv step:
//   S^T[kv][q] = mfma32(Kfrag, Qfrag)  (4 MFMA, k-dim = D = 64)
//   softmax per lane over 16 kv values + one shfl_xor(32) pair-combine
//   P packed in-register (lane-half exchange) -> B-operand of PV
//   O^T[d][q] += mfma32(V^Tfrag, Pfrag)  (4 MFMA)
// K/V/pos double-buffered in LDS via global_load_lds (pre-swizzled source, XOR-swizzled reads).
__global__ __launch_bounds__(256, 2) void attn_kernel(
    const half_t* __restrict__ qh, const half_t* __restrict__ kk,
    const half_t* __restrict__ vt, const float* __restrict__ pos,
    half_t* __restrict__ xout) {
  // per buffer: K 32x128B (4 KB) @0 | V^T 64x64B (4 KB) @4096 | pos 128x128B (16 KB) @8192
  __shared__ alignas(16) unsigned char smem[2][24576];

  const int tid  = threadIdx.x;
  const int lane = tid & 63;
  const int w    = tid >> 6;
  const int lr   = lane & 31;
  const int hi   = lane >> 5;

  const int bh  = blockIdx.x >> 3;
  const int q0b = (blockIdx.x & 7) * 128;
  const int q0w = q0b + w * 32;

  const char* kgb = (const char*)(kk + (size_t)bh * 2048 * 64);
  const char* vgb = (const char*)(vt + (size_t)bh * 64 * 2048);
  const char* pgb = (const char*)(pos + ((size_t)bh * 1024 + q0b) * 1024);

  // staging: linear LDS dest, inverse-swizzled global source (rule 21)
  const int krow = tid >> 3;                                   // 0..31
  const int kcsw = ((tid & 7) * 16) ^ ((krow & 7) << 4);
  const int vrow = tid >> 2;                                   // 0..63
  const int vcsw = ((tid & 3) * 16) ^ ((vrow & 3) << 4);

  // Q fragments in registers (B-operand: col=q=lane&31, k=d=ks*16+hi*8+j)
  half8 qf[4];
  {
    const half_t* qg = qh + ((size_t)bh * 1024 + q0w + lr) * 64 + hi * 8;
#pragma unroll
    for (int ks = 0; ks < 4; ++ks) qf[ks] = ld8(qg + ks * 16);
  }

  f32x16 oa0 = {}, oa1 = {};
  float m_run = -1e30f, l_run = 0.f;

  const float LOG2E = 1.4426950408889634f;
  const float SCL2E = 0.125f * 1.4426950408889634f;
  const int   kswz  = (lr & 7) << 4;
  const int   vswz  = (lr & 3) << 4;

  auto stage = [&](int buf, int kv0) {
    unsigned char* s = smem[buf];
    GLL16(kgb + (size_t)(kv0 + krow) * 128 + kcsw, s + tid * 16);
    GLL16(vgb + (size_t)vrow * 4096 + (size_t)kv0 * 2 + vcsw, s + 4096 + tid * 16);
    if (kv0 < 1024) {
#pragma unroll
      for (int i = 0; i < 4; ++i) {
        const int off  = (i * 256 + tid) * 16;
        const int prow = off >> 7;
        const int pc   = (off & 127) ^ ((prow & 7) << 4);
        GLL16(pgb + (size_t)prow * 4096 + (size_t)kv0 * 4 + pc, s + 8192 + off);
      }
    }
  };

  stage(0, 0);
  __syncthreads();

  for (int kv0 = 0; kv0 < 2048; kv0 += 32) {
    const int cur = (kv0 >> 5) & 1;
    const unsigned char* sb = smem[cur];
    if (kv0 + 32 < 2048) stage(cur ^ 1, kv0 + 32);

    // ---- S^T = K * Q^T  (rows kv, cols q), k-dim = D = 64
    f32x16 sreg = {};
#pragma unroll
    for (int ks = 0; ks < 4; ++ks) {
      const half8 kf = *(const half8*)(sb + lr * 128 + ((ks * 32 + hi * 16) ^ kswz));
      sreg = MFMA32(kf, qf[ks], sreg);
    }

    // ---- bias + log2-domain logits; reg r -> kv = (r&3) + 8*(r>>2) + 4*hi
    float lg[16];
    if (kv0 < 1024) {
      const unsigned char* sp = sb + 8192 + (size_t)(w * 32 + lr) * 128;
#pragma unroll
      for (int t = 0; t < 4; ++t) {
        const f32x4 pv = *(const f32x4*)(sp + ((t * 32 + hi * 16) ^ kswz));
#pragma unroll
        for (int u = 0; u < 4; ++u) lg[t * 4 + u] = sreg[t * 4 + u] * SCL2E + pv[u] * LOG2E;
      }
    } else {
#pragma unroll
      for (int r = 0; r < 16; ++r) lg[r] = sreg[r] * SCL2E;
    }

    // ---- online softmax: lane-local 16 + one pair combine across lane^32
    float mx = lg[0];
#pragma unroll
    for (int r = 1; r < 16; ++r) mx = fmaxf(mx, lg[r]);
    mx = fmaxf(mx, __shfl_xor(mx, 32));
    if (__any(mx > m_run)) {          // exact defer: alpha==1 for all lanes otherwise
      const float mnew  = fmaxf(m_run, mx);
      const float alpha = exp2f(m_run - mnew);
#pragma unroll
      for (int r = 0; r < 16; ++r) { oa0[r] *= alpha; oa1[r] *= alpha; }
      l_run *= alpha;
      m_run = mnew;
    }
    float pe[16];
    float rs = 0.f;
#pragma unroll
    for (int r = 0; r < 16; ++r) { pe[r] = exp2f(lg[r] - m_run); rs += pe[r]; }
    rs += __shfl_xor(rs, 32);
    l_run += rs;

    // ---- pack P -> PV B-operand (col=q, k=kv=m*16+hi*8+j), lane-half exchange
    unsigned int pk[8], xp[8];
#pragma unroll
    for (int e = 0; e < 8; ++e) {
      union { half2v h; unsigned int u; } cv;
      cv.h[0] = (half_t)pe[2 * e];
      cv.h[1] = (half_t)pe[2 * e + 1];
      pk[e] = cv.u;
    }
#pragma unroll
    for (int e = 0; e < 8; ++e) xp[e] = (unsigned int)__shfl_xor((int)pk[e], 32);

    union { unsigned int u[4]; half8 h; } bf0, bf1;
    if (hi) {
      bf0.u[0] = xp[2]; bf0.u[1] = xp[3]; bf0.u[2] = pk[2]; bf0.u[3] = pk[3];
      bf1.u[0] = xp[6]; bf1.u[1] = xp[7]; bf1.u[2] = pk[6]; bf1.u[3] = pk[7];
    } else {
      bf0.u[0] = pk[0]; bf0.u[1] = pk[1]; bf0.u[2] = xp[0]; bf0.u[3] = xp[1];
      bf1.u[0] = pk[4]; bf1.u[1] = pk[5]; bf1.u[2] = xp[4]; bf1.u[3] = xp[5];
    }

    // ---- O^T += V^T * P   (A rows = d, k = kv)
#pragma unroll
    for (int m = 0; m < 2; ++m) {
      const int co = (m * 32 + hi * 16) ^ vswz;
      const half8 vf0 = *(const half8*)(sb + 4096 + lr * 64 + co);
      const half8 vf1 = *(const half8*)(sb + 4096 + (32 + lr) * 64 + co);
      const half8 pb  = m ? bf1.h : bf0.h;
      oa0 = MFMA32(vf0, pb, oa0);
      oa1 = MFMA32(vf1, pb, oa1);
    }

    __syncthreads();   // drains stage's vmcnt + all waves done reading buf cur
  }

  // ---- epilogue: x[b, q, h*64 + d] = O^T[d][q] / l    (d = d0*32 + 8t + 4hi + u)
  const float inv = 1.0f / l_run;
  half_t* xg = xout + ((size_t)(bh >> 4) * 1024 + q0w + lr) * 1024 + (bh & 15) * 64;
#pragma unroll
  for (int t = 0; t < 4; ++t) {
    half4 h0, h1;
#pragma unroll
    for (int u = 0; u < 4; ++u) {
      h0[u] = (half_t)(oa0[t * 4 + u] * inv);
      h1[u] = (half_t)(oa1[t * 4 + u] * inv);
    }
    *(half4*)(xg + t * 8 + hi * 4)      = h0;
    *(half4*)(xg + 32 + t * 8 + hi * 4) = h1;
  }
}

// ---------------------------------------------------------------- launch
extern "C" void kernel_launch(void* const* d_in, const int* in_sizes, int n_in,
                              void* d_out, int out_size, void* d_ws, size_t ws_size,
                              hipStream_t stream) {
  const float* q   = (const float*)d_in[0];
  const float* kv  = (const float*)d_in[1];
  const float* pos = (const float*)d_in[2];
  const float* qw  = (const float*)d_in[3];
  const float* kvw = (const float*)d_in[4];
  const float* pw  = (const float*)d_in[5];
  const float* pb  = (const float*)d_in[6];
  float* out = (float*)d_out;

  char* ws = (char*)d_ws;
  half_t* qf   = (half_t*)(ws);
  half_t* kvf  = (half_t*)(ws + (size_t)(8)  * 1048576);
  half_t* qwf  = (half_t*)(ws + (size_t)(24) * 1048576);
  half_t* kvwf = (half_t*)(ws + (size_t)(26) * 1048576);
  half_t* pwf  = (half_t*)(ws + (size_t)(30) * 1048576);
  half_t* qh   = (half_t*)(ws + (size_t)(32) * 1048576);
  half_t* kk   = (half_t*)(ws + (size_t)(40) * 1048576);
  half_t* vt   = (half_t*)(ws + (size_t)(56) * 1048576);
  half_t* xb   = (half_t*)(ws + (size_t)(72) * 1048576);

  auto cvt = [&](const float* s, half_t* d, int n) {
    cvt_f32_f16<<<n / 1024, 256, 0, stream>>>(s, d, n / 4);
  };
  cvt(q,   qf,   4 * 1024 * 1024);
  cvt(kv,  kvf,  4 * 2048 * 1024);
  cvt(qw,  qwf,  1024 * 1024);
  cvt(kvw, kvwf, 2048 * 1024);
  cvt(pw,  pwf,  1024 * 1024);

  gemm_kernel<0><<<dim3(1024 / 128, 4096 / 128), 256, 0, stream>>>(
      qf, qwf, 4096, 1024, 1024, qh, nullptr, nullptr, nullptr);
  gemm_kernel<1><<<dim3(2048 / 128, 8192 / 128), 256, 0, stream>>>(
      kvf, kvwf, 8192, 2048, 1024, kk, vt, nullptr, nullptr);
  attn_kernel<<<4 * 16 * 8, 256, 0, stream>>>(qh, kk, vt, pos, xb);
  gemm_kernel<2><<<dim3(1024 / 128, 4096 / 128), 256, 0, stream>>>(
      xb, pwf, 4096, 1024, 1024, nullptr, nullptr, out, pb);
}

// Round 2
// 591.202 us; speedup vs baseline: 1.0469x; 1.0195x over previous
//
#include <hip/hip_runtime.h>

using half_t = _Float16;
using half8  = __attribute__((ext_vector_type(8))) _Float16;
using half4  = __attribute__((ext_vector_type(4))) _Float16;
using half2v = __attribute__((ext_vector_type(2))) _Float16;
using f32x4  = __attribute__((ext_vector_type(4))) float;
using f32x16 = __attribute__((ext_vector_type(16))) float;

#define MFMA(a, b, c)   __builtin_amdgcn_mfma_f32_16x16x32_f16((a), (b), (c), 0, 0, 0)
#define MFMA32(a, b, c) __builtin_amdgcn_mfma_f32_32x32x16_f16((a), (b), (c), 0, 0, 0)

// async global->LDS, 16 B per lane. LDS dest = wave-uniform base + lane*16.
#define GLL16(g, l)                                                     \
  __builtin_amdgcn_global_load_lds(                                     \
      (__attribute__((address_space(1))) void*)(g),                     \
      (__attribute__((address_space(3))) void*)(l), 16, 0, 0)

// fused "wait own async loads down to N, then barrier" — single opaque asm so
// no memory op (ds_read / GLL issue) can be scheduled across any part of it.
#define WAITBAR(n) asm volatile("s_waitcnt vmcnt(" #n ")\n\ts_barrier" ::: "memory")

__device__ __forceinline__ half8 ld8(const half_t* p) { return *(const half8*)p; }

// ---------------------------------------------------------------- convert
__global__ void cvt_f32_f16(const float* __restrict__ src, half_t* __restrict__ dst, int n4) {
  int i = blockIdx.x * blockDim.x + threadIdx.x;
  if (i < n4) {
    f32x4 v = ((const f32x4*)src)[i];
    half4 h;
    h[0] = (half_t)v[0]; h[1] = (half_t)v[1]; h[2] = (half_t)v[2]; h[3] = (half_t)v[3];
    ((half4*)dst)[i] = h;
  }
}

// ---------------------------------------------------------------- GEMM (C = A * Bt^T), m97 structure
template <int EPI>
__global__ __launch_bounds__(256) void gemm_kernel(
    const half_t* __restrict__ A, const half_t* __restrict__ Bt,
    int M, int N, int K,
    half_t* __restrict__ oh, half_t* __restrict__ ov,
    float* __restrict__ of, const float* __restrict__ bias) {
  __shared__ alignas(16) half_t sA[128 * 32];
  __shared__ alignas(16) half_t sB[128 * 32];
  const int tid  = threadIdx.x;
  const int lane = tid & 63;
  const int w    = tid >> 6;
  const int c    = lane & 15;
  const int quad = lane >> 4;
  const int m0 = blockIdx.y * 128;
  const int n0 = blockIdx.x * 128;
  const int wm = (w & 1) * 64;
  const int wn = (w >> 1) * 64;

  f32x4 acc[4][4] = {};

  const int srow = tid >> 2;
  const int scol = (tid & 3) * 8;
  const half_t* Ag = A + (size_t)(m0 + srow) * K + scol;
  const half_t* Bg = Bt + (size_t)(n0 + srow) * K + scol;

  for (int k0 = 0; k0 < K; k0 += 32) {
    GLL16(Ag + k0,            sA + tid * 8);
    GLL16(Ag + k0 + 64 * K,   sA + tid * 8 + 2048);
    GLL16(Bg + k0,            sB + tid * 8);
    GLL16(Bg + k0 + 64 * K,   sB + tid * 8 + 2048);
    __syncthreads();
    half8 a[4], b[4];
#pragma unroll
    for (int i = 0; i < 4; ++i) a[i] = ld8(&sA[(wm + i * 16 + c) * 32 + quad * 8]);
#pragma unroll
    for (int j = 0; j < 4; ++j) b[j] = ld8(&sB[(wn + j * 16 + c) * 32 + quad * 8]);
#pragma unroll
    for (int i = 0; i < 4; ++i)
#pragma unroll
      for (int j = 0; j < 4; ++j) acc[i][j] = MFMA(a[i], b[j], acc[i][j]);
    __syncthreads();
  }

#pragma unroll
  for (int i = 0; i < 4; ++i) {
    const int mbase = m0 + wm + i * 16 + quad * 4;
#pragma unroll
    for (int j = 0; j < 4; ++j) {
      const int n = n0 + wn + j * 16 + c;
      if (EPI == 0) {
        const int bb = mbase >> 10, qi = mbase & 1023;
        const int hh = n >> 6, d = n & 63;
        half_t* p = oh + (((size_t)(bb * 16 + hh) * 1024 + qi) * 64 + d);
#pragma unroll
        for (int r = 0; r < 4; ++r) p[(size_t)r * 64] = (half_t)acc[i][j][r];
      } else if (EPI == 1) {
        const int bb = mbase >> 11, kvi = mbase & 2047;
        if (n < 1024) {
          const int hh = n >> 6, d = n & 63;
          half_t* p = oh + (((size_t)(bb * 16 + hh) * 2048 + kvi) * 64 + d);
#pragma unroll
          for (int r = 0; r < 4; ++r) p[(size_t)r * 64] = (half_t)acc[i][j][r];
        } else {
          const int nn = n - 1024;
          const int hh = nn >> 6, d = nn & 63;
          half4 hv;
#pragma unroll
          for (int r = 0; r < 4; ++r) hv[r] = (half_t)acc[i][j][r];
          *(half4*)&ov[((size_t)(bb * 16 + hh) * 64 + d) * 2048 + kvi] = hv;
        }
      } else {
        const float bv = bias[n];
#pragma unroll
        for (int r = 0; r < 4; ++r) of[(size_t)(mbase + r) * N + n] = acc[i][j][r] + bv;
      }
    }
  }
}

// ---------------------------------------------------------------- flash attention, swapped-QK 32x32 structure
// grid: bh*8 + qblk, 256 threads = 4 waves, 32 q-rows/wave.
// Triple-buffered K/V/pos staging via global_load_lds with counted-vmcnt pipeline
// (2 stages in flight across barriers; never drains to 0 in the main loop).
// per buffer: K 32x128B @0 | V packed 32x128B (row r = [V^T[r] | V^T[r+32]]) @4096 | pos 128x128B @8192
__global__ __launch_bounds__(256, 2) void attn_kernel(
    const half_t* __restrict__ qh, const half_t* __restrict__ kk,
    const half_t* __restrict__ vt, const float* __restrict__ pos,
    half_t* __restrict__ xout) {
  __shared__ alignas(16) unsigned char smem[3][24576];

  const int tid  = threadIdx.x;
  const int lane = tid & 63;
  const int w    = tid >> 6;
  const int lr   = lane & 31;
  const int hi   = lane >> 5;

  const int bh  = blockIdx.x >> 3;
  const int q0b = (blockIdx.x & 7) * 128;
  const int q0w = q0b + w * 32;

  const char* kgb = (const char*)(kk + (size_t)bh * 2048 * 64);
  const char* vgb = (const char*)(vt + (size_t)bh * 64 * 2048);
  const char* pgb = (const char*)(pos + ((size_t)bh * 1024 + q0b) * 1024);

  // staging geometry: linear LDS dest, inverse-swizzled global source (rule 21)
  const int krow = tid >> 3;                                   // 0..31
  const int kcsw = ((tid & 7) * 16) ^ ((krow & 7) << 4);
  const int vrow = tid >> 3;                                   // 0..31
  const int vlc  = ((tid & 7) * 16) ^ ((vrow & 7) << 4);       // logical col byte 0..127
  const char* vsrc = vgb + (size_t)(vrow + ((vlc >> 6) << 5)) * 4096 + (vlc & 63);

  // Q fragments in registers (B-operand: col=q=lane&31, k=d=ks*16+hi*8+j)
  half8 qf[4];
  {
    const half_t* qg = qh + ((size_t)bh * 1024 + q0w + lr) * 64 + hi * 8;
#pragma unroll
    for (int ks = 0; ks < 4; ++ks) qf[ks] = ld8(qg + ks * 16);
  }
  asm volatile("s_waitcnt vmcnt(0)" ::: "memory");  // qf drained -> exact GLL counting

  f32x16 oa0 = {}, oa1 = {};
  float m_run = -1e30f, l_run = 0.f;

  const float LOG2E = 1.4426950408889634f;
  const float SCL2E = 0.125f * 1.4426950408889634f;
  const int   kswz  = (lr & 7) << 4;

  // per-thread GLL count: 6 when kv0<1024 (K+V+4*pos), else 2
  auto stage = [&](int buf, int kv0) {
    unsigned char* s = smem[buf];
    GLL16(kgb + (size_t)(kv0 + krow) * 128 + kcsw, s + tid * 16);
    GLL16(vsrc + (size_t)kv0 * 2, s + 4096 + tid * 16);
    if (kv0 < 1024) {
#pragma unroll
      for (int i = 0; i < 4; ++i) {
        const int off  = (i * 256 + tid) * 16;
        const int prow = off >> 7;
        const int pc   = (off & 127) ^ ((prow & 7) << 4);
        GLL16(pgb + (size_t)prow * 4096 + (size_t)kv0 * 4 + pc, s + 8192 + off);
      }
    }
  };

  auto compute = [&](const unsigned char* sb, int kv0) {
    // ---- S^T = K * Q^T  (rows kv, cols q), k-dim = D = 64
    f32x16 sreg = {};
#pragma unroll
    for (int ks = 0; ks < 4; ++ks) {
      const half8 kf = *(const half8*)(sb + lr * 128 + ((ks * 32 + hi * 16) ^ kswz));
      sreg = MFMA32(kf, qf[ks], sreg);
    }

    // ---- bias + log2-domain logits; reg r -> kv = (r&3) + 8*(r>>2) + 4*hi
    float lg[16];
    if (kv0 < 1024) {
      const unsigned char* sp = sb + 8192 + (size_t)(w * 32 + lr) * 128;
#pragma unroll
      for (int t = 0; t < 4; ++t) {
        const f32x4 pv = *(const f32x4*)(sp + ((t * 32 + hi * 16) ^ kswz));
#pragma unroll
        for (int u = 0; u < 4; ++u) lg[t * 4 + u] = sreg[t * 4 + u] * SCL2E + pv[u] * LOG2E;
      }
    } else {
#pragma unroll
      for (int r = 0; r < 16; ++r) lg[r] = sreg[r] * SCL2E;
    }

    // ---- online softmax: lane-local 16 + one pair combine across lane^32
    float mx = lg[0];
#pragma unroll
    for (int r = 1; r < 16; ++r) mx = fmaxf(mx, lg[r]);
    mx = fmaxf(mx, __shfl_xor(mx, 32));
    if (__any(mx > m_run)) {          // exact defer: alpha==1 for all lanes otherwise
      const float mnew  = fmaxf(m_run, mx);
      const float alpha = exp2f(m_run - mnew);
#pragma unroll
      for (int r = 0; r < 16; ++r) { oa0[r] *= alpha; oa1[r] *= alpha; }
      l_run *= alpha;
      m_run = mnew;
    }
    float pe[16];
    float rs = 0.f;
#pragma unroll
    for (int r = 0; r < 16; ++r) { pe[r] = exp2f(lg[r] - m_run); rs += pe[r]; }
    rs += __shfl_xor(rs, 32);
    l_run += rs;

    // ---- pack P -> PV B-operand (col=q, k=kv=m*16+hi*8+j), lane-half exchange
    unsigned int pk[8], xp[8];
#pragma unroll
    for (int e = 0; e < 8; ++e) {
      union { half2v h; unsigned int u; } cv;
      cv.h[0] = (half_t)pe[2 * e];
      cv.h[1] = (half_t)pe[2 * e + 1];
      pk[e] = cv.u;
    }
#pragma unroll
    for (int e = 0; e < 8; ++e) xp[e] = (unsigned int)__shfl_xor((int)pk[e], 32);

    union { unsigned int u[4]; half8 h; } bf0, bf1;
    if (hi) {
      bf0.u[0] = xp[2]; bf0.u[1] = xp[3]; bf0.u[2] = pk[2]; bf0.u[3] = pk[3];
      bf1.u[0] = xp[6]; bf1.u[1] = xp[7]; bf1.u[2] = pk[6]; bf1.u[3] = pk[7];
    } else {
      bf0.u[0] = pk[0]; bf0.u[1] = pk[1]; bf0.u[2] = xp[0]; bf0.u[3] = xp[1];
      bf1.u[0] = pk[4]; bf1.u[1] = pk[5]; bf1.u[2] = xp[4]; bf1.u[3] = xp[5];
    }

    // ---- O^T += V^T * P   (A rows = d, k = kv); V packed row lr = [d=lr | d=lr+32]
    const unsigned char* sv = sb + 4096 + lr * 128;
#pragma unroll
    for (int m = 0; m < 2; ++m) {
      const half8 vf0 = *(const half8*)(sv + ((m * 32 + hi * 16) ^ kswz));
      const half8 vf1 = *(const half8*)(sv + ((64 + m * 32 + hi * 16) ^ kswz));
      const half8 pb  = m ? bf1.h : bf0.h;
      oa0 = MFMA32(vf0, pb, oa0);
      oa1 = MFMA32(vf1, pb, oa1);
    }
  };

  // ---- pipelined main loop: 2 stages in flight, counted vmcnt, never drain-0
  stage(0, 0);
  stage(1, 32);
  int kv0 = 0;
  for (int k = 0; k < 31; ++k, kv0 += 32) {   // stages k..k+1 heavy in flight
    WAITBAR(6);
    stage((k + 2) % 3, kv0 + 64);
    compute(smem[k % 3], kv0);
  }
  for (int k = 31; k < 63; ++k, kv0 += 32) {  // light stages (2 GLL) in flight
    WAITBAR(2);
    if (k < 62) stage((k + 2) % 3, kv0 + 64);
    compute(smem[k % 3], kv0);
  }
  WAITBAR(0);
  compute(smem[0], kv0);                       // k = 63, 63 % 3 == 0

  // ---- epilogue: x[b, q, h*64 + d] = O^T[d][q] / l    (d = d0*32 + 8t + 4hi + u)
  const float inv = 1.0f / l_run;
  half_t* xg = xout + ((size_t)(bh >> 4) * 1024 + q0w + lr) * 1024 + (bh & 15) * 64;
#pragma unroll
  for (int t = 0; t < 4; ++t) {
    half4 h0, h1;
#pragma unroll
    for (int u = 0; u < 4; ++u) {
      h0[u] = (half_t)(oa0[t * 4 + u] * inv);
      h1[u] = (half_t)(oa1[t * 4 + u] * inv);
    }
    *(half4*)(xg + t * 8 + hi * 4)      = h0;
    *(half4*)(xg + 32 + t * 8 + hi * 4) = h1;
  }
}

// ---------------------------------------------------------------- launch
extern "C" void kernel_launch(void* const* d_in, const int* in_sizes, int n_in,
                              void* d_out, int out_size, void* d_ws, size_t ws_size,
                              hipStream_t stream) {
  const float* q   = (const float*)d_in[0];
  const float* kv  = (const float*)d_in[1];
  const float* pos = (const float*)d_in[2];
  const float* qw  = (const float*)d_in[3];
  const float* kvw = (const float*)d_in[4];
  const float* pw  = (const float*)d_in[5];
  const float* pb  = (const float*)d_in[6];
  float* out = (float*)d_out;

  char* ws = (char*)d_ws;
  half_t* qf   = (half_t*)(ws);
  half_t* kvf  = (half_t*)(ws + (size_t)(8)  * 1048576);
  half_t* qwf  = (half_t*)(ws + (size_t)(24) * 1048576);
  half_t* kvwf = (half_t*)(ws + (size_t)(26) * 1048576);
  half_t* pwf  = (half_t*)(ws + (size_t)(30) * 1048576);
  half_t* qh   = (half_t*)(ws + (size_t)(32) * 1048576);
  half_t* kk   = (half_t*)(ws + (size_t)(40) * 1048576);
  half_t* vt   = (half_t*)(ws + (size_t)(56) * 1048576);
  half_t* xb   = (half_t*)(ws + (size_t)(72) * 1048576);

  auto cvt = [&](const float* s, half_t* d, int n) {
    cvt_f32_f16<<<n / 1024, 256, 0, stream>>>(s, d, n / 4);
  };
  cvt(q,   qf,   4 * 1024 * 1024);
  cvt(kv,  kvf,  4 * 2048 * 1024);
  cvt(qw,  qwf,  1024 * 1024);
  cvt(kvw, kvwf, 2048 * 1024);
  cvt(pw,  pwf,  1024 * 1024);

  gemm_kernel<0><<<dim3(1024 / 128, 4096 / 128), 256, 0, stream>>>(
      qf, qwf, 4096, 1024, 1024, qh, nullptr, nullptr, nullptr);
  gemm_kernel<1><<<dim3(2048 / 128, 8192 / 128), 256, 0, stream>>>(
      kvf, kvwf, 8192, 2048, 1024, kk, vt, nullptr, nullptr);
  attn_kernel<<<4 * 16 * 8, 256, 0, stream>>>(qh, kk, vt, pos, xb);
  gemm_kernel<2><<<dim3(1024 / 128, 4096 / 128), 256, 0, stream>>>(
      xb, pwf, 4096, 1024, 1024, nullptr, nullptr, out, pb);
}